// Round 2
// baseline (22678.087 us; speedup 1.0000x reference)
//
#include <hip/hip_runtime.h>

#define NBATCH 128
#define DMODEL 512
#define FDIM 64
#define KIN 1024
#define NOUT 2048

struct Par {
  const float *input, *mask, *Wi, *bi, *gi, *bti;
  const float *Wd1, *bd1, *Wd2, *bd2;
  const float *Wc1, *bc1, *Wc2, *bc2, *gc, *btc;
  float *out;
  float *cs, *x, *h, *ct, *logits;
  int *pos, *ksel;
  unsigned int *bar;
};

__device__ __forceinline__ float gelu_f(float v) {
  float u = 0.7978845608028654f * (v + 0.044715f * v * v * v);
  return 0.5f * v * (1.0f + tanhf(u));
}
__device__ __forceinline__ float sigm_f(float v) { return 1.0f / (1.0f + expf(-v)); }

__device__ __forceinline__ float wred_sum(float v) {
#pragma unroll
  for (int o = 32; o > 0; o >>= 1) v += __shfl_xor(v, o, 64);
  return v;
}

// monotonic-counter grid barrier (blocks must be co-resident; grid=256=#CUs)
__device__ __forceinline__ void gsync(unsigned int* bar, unsigned int* tgt) {
  __syncthreads();
  if (threadIdx.x == 0) {
    *tgt += gridDim.x;
    __hip_atomic_fetch_add(bar, 1u, __ATOMIC_ACQ_REL, __HIP_MEMORY_SCOPE_AGENT);
    while (__hip_atomic_load(bar, __ATOMIC_ACQUIRE, __HIP_MEMORY_SCOPE_AGENT) < *tgt)
      __builtin_amdgcn_s_sleep(1);
  }
  __syncthreads();
}

// ---- SEL: argmax + pos/logit shift + build x = [l_sel, r_sel] (one block per row)
__device__ void sel_phase(const Par& p, int i, int* sI) {
  int n = blockIdx.x;
  int t = threadIdx.x, wave = t >> 6, lane = t & 63;
  int P = 63 - i;  // pair count this iteration
  if (wave == 0) {
    float v = -3.0e38f;
    int idx = 1 << 20;
    if (lane < P) {
      v = p.logits[n * 64 + lane];
      float mk = p.mask[n * 64 + i + 1 + lane];
      if (!(mk > 0.0f)) v = -1.0e9f;
      idx = lane;
    }
#pragma unroll
    for (int o = 32; o > 0; o >>= 1) {
      float v2 = __shfl_xor(v, o, 64);
      int i2 = __shfl_xor(idx, o, 64);
      if (v2 > v || (v2 == v && i2 < idx)) { v = v2; idx = i2; }
    }
    if (lane == 0) {
      p.ksel[n] = idx;
      sI[0] = idx;
      sI[1] = p.pos[n * 64 + idx];
      sI[2] = p.pos[n * 64 + idx + 1];
    }
  }
  __syncthreads();
  int k = sI[0], slot_l = sI[1], slot_r = sI[2];
  // shift pos left for j>=k+1 (wave-lockstep load-before-store is safe)
  if (wave == 1) {
    int j = lane;
    if (j >= k + 1 && j <= 62 - i) {
      int tmp = p.pos[n * 64 + j + 1];
      p.pos[n * 64 + j] = tmp;
    }
  } else if (wave == 2) {
    int j = lane;
    if (j >= k && j <= 61 - i) {
      float tmp = p.logits[n * 64 + j + 1];
      p.logits[n * 64 + j] = tmp;
    }
  }
  // x[n] = concat(cs[slot_l], cs[slot_r])
  const float4* csl = (const float4*)&p.cs[(size_t)(n * 64 + slot_l) * DMODEL];
  const float4* csr = (const float4*)&p.cs[(size_t)(n * 64 + slot_r) * DMODEL];
  float4* xd = (float4*)&p.x[(size_t)n * KIN];
  if (t < 128) xd[t] = csl[t];
  else xd[t] = csr[t - 128];
}

// ---- GEMM1: h = gelu(x @ Wc1 + bc1); 8 Mtiles(16 rows) x 32 Nchunks(64 cols)
//      K staged in two 512-col halves (32 KB LDS each)
__device__ void g1_phase(const Par& p, float* smem) {
  int b = blockIdx.x, t = threadIdx.x;
  int mt = b >> 5, nc = b & 31;
  int rbase = mt * 16, cbase = nc * 64;
  float* xs = smem;  // [16][512]
  int cc = (t & 31) * 2;
  int rg = t >> 5;
  int r0 = rg * 2, r1 = r0 + 1;
  int cg = cbase + cc;
  int wcol = cg >> 1;
  const float2* W2 = (const float2*)p.Wc1;
  float a00 = 0, a01 = 0, a10 = 0, a11 = 0;
  for (int half = 0; half < 2; ++half) {
    __syncthreads();
#pragma unroll
    for (int q = 0; q < 8; ++q) {
      int i4 = q * 256 + t;
      int flat = i4 * 4;
      int r = flat >> 9, c = flat & 511;
      *(float4*)&xs[flat] =
          *(const float4*)&p.x[(size_t)(rbase + r) * KIN + half * 512 + c];
    }
    __syncthreads();
    const float* x0 = xs + r0 * 512;
    const float* x1 = xs + r1 * 512;
    for (int k = 0; k < 512; k += 4) {
      int kr = half * 512 + k;
      float4 xa = *(const float4*)&x0[k];
      float4 xb = *(const float4*)&x1[k];
      float2 w0 = W2[(size_t)(kr + 0) * (NOUT / 2) + wcol];
      float2 w1 = W2[(size_t)(kr + 1) * (NOUT / 2) + wcol];
      float2 w2 = W2[(size_t)(kr + 2) * (NOUT / 2) + wcol];
      float2 w3 = W2[(size_t)(kr + 3) * (NOUT / 2) + wcol];
      a00 += xa.x * w0.x; a00 += xa.y * w1.x; a00 += xa.z * w2.x; a00 += xa.w * w3.x;
      a01 += xa.x * w0.y; a01 += xa.y * w1.y; a01 += xa.z * w2.y; a01 += xa.w * w3.y;
      a10 += xb.x * w0.x; a10 += xb.y * w1.x; a10 += xb.z * w2.x; a10 += xb.w * w3.x;
      a11 += xb.x * w0.y; a11 += xb.y * w1.y; a11 += xb.z * w2.y; a11 += xb.w * w3.y;
    }
  }
  float2 bc = *(const float2*)&p.bc1[cg];
  float2 o0 = make_float2(gelu_f(a00 + bc.x), gelu_f(a01 + bc.y));
  float2 o1 = make_float2(gelu_f(a10 + bc.x), gelu_f(a11 + bc.y));
  *(float2*)&p.h[(size_t)(rbase + r0) * NOUT + cg] = o0;
  *(float2*)&p.h[(size_t)(rbase + r1) * NOUT + cg] = o1;
}

// ---- GEMM2: ct = h @ Wc2 + bc2 (K=2048 staged in four 512-col quarters)
__device__ void g2_phase(const Par& p, float* smem) {
  int b = blockIdx.x, t = threadIdx.x;
  int mt = b >> 5, nc = b & 31;
  int rbase = mt * 16, cbase = nc * 64;
  float* hs = smem;  // [16][512]
  int cc = (t & 31) * 2;
  int rg = t >> 5;
  int r0 = rg * 2, r1 = r0 + 1;
  int cg = cbase + cc;
  int wcol = cg >> 1;
  const float2* W2 = (const float2*)p.Wc2;
  float a00 = 0, a01 = 0, a10 = 0, a11 = 0;
  for (int qtr = 0; qtr < 4; ++qtr) {
    __syncthreads();
#pragma unroll
    for (int q = 0; q < 8; ++q) {
      int i4 = q * 256 + t;
      int flat = i4 * 4;
      int r = flat >> 9, c = flat & 511;
      *(float4*)&hs[flat] =
          *(const float4*)&p.h[(size_t)(rbase + r) * NOUT + qtr * 512 + c];
    }
    __syncthreads();
    const float* x0 = hs + r0 * 512;
    const float* x1 = hs + r1 * 512;
    for (int k = 0; k < 512; k += 4) {
      int kr = qtr * 512 + k;
      float4 xa = *(const float4*)&x0[k];
      float4 xb = *(const float4*)&x1[k];
      float2 w0 = W2[(size_t)(kr + 0) * (NOUT / 2) + wcol];
      float2 w1 = W2[(size_t)(kr + 1) * (NOUT / 2) + wcol];
      float2 w2 = W2[(size_t)(kr + 2) * (NOUT / 2) + wcol];
      float2 w3 = W2[(size_t)(kr + 3) * (NOUT / 2) + wcol];
      a00 += xa.x * w0.x; a00 += xa.y * w1.x; a00 += xa.z * w2.x; a00 += xa.w * w3.x;
      a01 += xa.x * w0.y; a01 += xa.y * w1.y; a01 += xa.z * w2.y; a01 += xa.w * w3.y;
      a10 += xb.x * w0.x; a10 += xb.y * w1.x; a10 += xb.z * w2.x; a10 += xb.w * w3.x;
      a11 += xb.x * w0.y; a11 += xb.y * w1.y; a11 += xb.z * w2.y; a11 += xb.w * w3.y;
    }
  }
  float2 bc = *(const float2*)&p.bc2[cg];
  *(float2*)&p.ct[(size_t)(rbase + r0) * NOUT + cg] = make_float2(a00 + bc.x, a01 + bc.y);
  *(float2*)&p.ct[(size_t)(rbase + r1) * NOUT + cg] = make_float2(a10 + bc.x, a11 + bc.y);
}

// ---- EPI: gates/blend/LN -> cs[slot_new]; recompute logits for pairs k-1, k
__device__ void epi_phase(const Par& p, int i, float* smem, float* sred) {
  int n = blockIdx.x;
  int t = threadIdx.x, wave = t >> 6, lane = t & 63;
  int Pn = 62 - i;  // pair count after this merge
  int k = p.ksel[n];
  int slot_new = p.pos[n * 64 + k];
  float* s_wd1 = smem;          // 8192
  float* s_wd2 = smem + 8192;   // 64
  float* s_bd1 = smem + 8256;   // 64
  float* s_fnew = smem + 8320;  // 64
  if (i < 62) {
#pragma unroll
    for (int q = 0; q < 8; ++q) {
      int i4 = q * 256 + t;
      ((float4*)s_wd1)[i4] = ((const float4*)p.Wd1)[i4];
    }
    if (t < 64) { s_wd2[t] = p.Wd2[t]; s_bd1[t] = p.bd1[t]; }
  }
  const float* ct = p.ct + (size_t)n * NOUT;
  int d0 = 2 * t, d1 = 2 * t + 1;
  float2 lv = *(const float2*)&p.x[(size_t)n * KIN + d0];
  float2 rv = *(const float2*)&p.x[(size_t)n * KIN + DMODEL + d0];
  float2 c0 = *(const float2*)&ct[d0];
  float2 c1 = *(const float2*)&ct[DMODEL + d0];
  float2 c2 = *(const float2*)&ct[2 * DMODEL + d0];
  float2 c3 = *(const float2*)&ct[3 * DMODEL + d0];
  float s0 = sigm_f(c0.x) * lv.x + sigm_f(c1.x) * rv.x + sigm_f(c2.x) * c3.x;
  float s1 = sigm_f(c0.y) * lv.y + sigm_f(c1.y) * rv.y + sigm_f(c2.y) * c3.y;
  float part = wred_sum(s0 + s1);
  if (lane == 0) sred[wave] = part;
  __syncthreads();
  float m = (sred[0] + sred[1] + sred[2] + sred[3]) * (1.0f / 512.0f);
  float e0 = s0 - m, e1 = s1 - m;
  float pq = wred_sum(e0 * e0 + e1 * e1);
  if (lane == 0) sred[4 + wave] = pq;
  __syncthreads();
  float var = (sred[4] + sred[5] + sred[6] + sred[7]) * (1.0f / 512.0f);
  float inv = 1.0f / sqrtf(var + 1e-5f);
  float nv0 = e0 * inv * p.gc[d0] + p.btc[d0];
  float nv1 = e1 * inv * p.gc[d1] + p.btc[d1];
  float* dst = &p.cs[(size_t)(n * 64 + slot_new) * DMODEL];
  dst[d0] = nv0;
  dst[d1] = nv1;
  if (i == 62) {
    p.out[(size_t)n * DMODEL + d0] = nv0;
    p.out[(size_t)n * DMODEL + d1] = nv1;
  }
  if (d0 < FDIM) { s_fnew[d0] = nv0; s_fnew[d1] = nv1; }
  __syncthreads();
  if (i < 62) {
    if (wave == 0 && k >= 1) {
      const float* A = &p.cs[(size_t)(n * 64 + p.pos[n * 64 + (k - 1)]) * DMODEL];
      float hs = s_bd1[lane];
#pragma unroll 8
      for (int kk = 0; kk < 64; ++kk) hs += A[kk] * s_wd1[kk * 64 + lane];
#pragma unroll 8
      for (int kk = 0; kk < 64; ++kk) hs += s_fnew[kk] * s_wd1[(64 + kk) * 64 + lane];
      float g = wred_sum(gelu_f(hs) * s_wd2[lane]);
      if (lane == 0) p.logits[n * 64 + (k - 1)] = g + p.bd2[0];
    } else if (wave == 1 && k < Pn) {
      const float* Bv = &p.cs[(size_t)(n * 64 + p.pos[n * 64 + (k + 1)]) * DMODEL];
      float hs = s_bd1[lane];
#pragma unroll 8
      for (int kk = 0; kk < 64; ++kk) hs += s_fnew[kk] * s_wd1[kk * 64 + lane];
#pragma unroll 8
      for (int kk = 0; kk < 64; ++kk) hs += Bv[kk] * s_wd1[(64 + kk) * 64 + lane];
      float g = wred_sum(gelu_f(hs) * s_wd2[lane]);
      if (lane == 0) p.logits[n * 64 + k] = g + p.bd2[0];
    }
  }
}

__global__ void egt_zero(unsigned int* bar) { bar[threadIdx.x] = 0u; }

__global__ void __launch_bounds__(256, 1) egt_main(Par p) {
  __shared__ __align__(16) float smem[12480];  // 49.9 KB  (< 64 KB block limit!)
  __shared__ float sred[16];
  __shared__ int sI[8];
  unsigned int nsync = 0;
  int b = blockIdx.x, t = threadIdx.x;
  int wave = t >> 6, lane = t & 63;

  // ---------- INIT-PROJ: cs0 = LN(input @ Wi + bi) ; 32 (n,s)-rows per block
  {
    int rbase = b * 32;
    int n_ = rbase >> 6;
    float acc[32][2];
#pragma unroll
    for (int r = 0; r < 32; ++r) { acc[r][0] = 0.0f; acc[r][1] = 0.0f; }
    float* xs = smem;  // [32][64]
    const float2* W2 = (const float2*)p.Wi;  // [512][256]
    for (int kc = 0; kc < 512; kc += 64) {
      __syncthreads();
#pragma unroll
      for (int q = 0; q < 2; ++q) {
        int i4 = q * 256 + t;
        int flat = i4 * 4;
        int r = flat >> 6, c = flat & 63;
        *(float4*)&xs[flat] = *(const float4*)&p.input[(size_t)(rbase + r) * 512 + kc + c];
      }
      __syncthreads();
      for (int k = 0; k < 64; k += 4) {
        float2 w0 = W2[(size_t)(kc + k + 0) * 256 + t];
        float2 w1 = W2[(size_t)(kc + k + 1) * 256 + t];
        float2 w2 = W2[(size_t)(kc + k + 2) * 256 + t];
        float2 w3 = W2[(size_t)(kc + k + 3) * 256 + t];
#pragma unroll
        for (int r = 0; r < 32; ++r) {
          float4 xv = *(const float4*)&xs[r * 64 + k];
          float sA = acc[r][0];
          sA += xv.x * w0.x; sA += xv.y * w1.x; sA += xv.z * w2.x; sA += xv.w * w3.x;
          acc[r][0] = sA;
          float sB = acc[r][1];
          sB += xv.x * w0.y; sB += xv.y * w1.y; sB += xv.z * w2.y; sB += xv.w * w3.y;
          acc[r][1] = sB;
        }
      }
    }
    float* row8 = smem;  // [8][512]
#pragma unroll
    for (int chunk = 0; chunk < 4; ++chunk) {
      __syncthreads();
#pragma unroll
      for (int rr = 0; rr < 8; ++rr) {
        int r = chunk * 8 + rr;
        row8[rr * 512 + 2 * t] = acc[r][0] + p.bi[2 * t];
        row8[rr * 512 + 2 * t + 1] = acc[r][1] + p.bi[2 * t + 1];
      }
      __syncthreads();
#pragma unroll
      for (int q = 0; q < 2; ++q) {
        int rr = wave * 2 + q;
        float vals[8];
        float sum = 0;
#pragma unroll
        for (int jj = 0; jj < 8; ++jj) {
          float v = row8[rr * 512 + jj * 64 + lane];
          vals[jj] = v;
          sum += v;
        }
        sum = wred_sum(sum);
        float mm = sum * (1.0f / 512.0f);
        float sq = 0;
#pragma unroll
        for (int jj = 0; jj < 8; ++jj) { float d = vals[jj] - mm; sq += d * d; }
        sq = wred_sum(sq);
        float inv = 1.0f / sqrtf(sq * (1.0f / 512.0f) + 1e-5f);
        int r = chunk * 8 + rr;
        int ss = (b & 1) * 32 + r;
        float* dst = &p.cs[(size_t)(n_ * 64 + ss) * 512];
#pragma unroll
        for (int jj = 0; jj < 8; ++jj) {
          int c = jj * 64 + lane;
          dst[c] = (vals[jj] - mm) * inv * p.gi[c] + p.bti[c];
        }
      }
    }
  }
  gsync(p.bar, &nsync);

  // ---------- INIT-SCORE: all 63 pair logits per row; init pos; SEL(0)
  if (b < NBATCH) {
    int n = b;
    float* s_wd1 = smem;          // 8192
    float* s_f = smem + 8192;     // 4096
    float* s_wd2 = smem + 12288;  // 64
    float* s_bd1 = smem + 12352;  // 64
#pragma unroll
    for (int q = 0; q < 8; ++q) {
      int i4 = q * 256 + t;
      ((float4*)s_wd1)[i4] = ((const float4*)p.Wd1)[i4];
    }
#pragma unroll
    for (int q = 0; q < 4; ++q) {
      int i4 = q * 256 + t;
      int flat = i4 * 4;
      int s = flat >> 6, c = flat & 63;
      *(float4*)&s_f[flat] = *(const float4*)&p.cs[(size_t)(n * 64 + s) * 512 + c];
    }
    if (t < 64) {
      s_wd2[t] = p.Wd2[t];
      s_bd1[t] = p.bd1[t];
      p.pos[n * 64 + t] = t;
    }
    __syncthreads();
    for (int pr = wave; pr < 63; pr += 4) {
      float hs = s_bd1[lane];
#pragma unroll 8
      for (int kk = 0; kk < 64; ++kk) hs += s_f[pr * 64 + kk] * s_wd1[kk * 64 + lane];
#pragma unroll 8
      for (int kk = 0; kk < 64; ++kk) hs += s_f[(pr + 1) * 64 + kk] * s_wd1[(64 + kk) * 64 + lane];
      float g = wred_sum(gelu_f(hs) * s_wd2[lane]);
      if (lane == 0) p.logits[n * 64 + pr] = g + p.bd2[0];
    }
    __syncthreads();
    sel_phase(p, 0, sI);
  }
  gsync(p.bar, &nsync);

  // ---------- main serial loop
  for (int i = 0; i < 63; ++i) {
    g1_phase(p, smem);
    gsync(p.bar, &nsync);
    g2_phase(p, smem);
    gsync(p.bar, &nsync);
    if (b < NBATCH) {
      epi_phase(p, i, smem, sred);
      if (i < 62) {
        __syncthreads();
        sel_phase(p, i + 1, sI);
      }
    }
    gsync(p.bar, &nsync);
  }
}

extern "C" void kernel_launch(void* const* d_in, const int* in_sizes, int n_in,
                              void* d_out, int out_size, void* d_ws, size_t ws_size,
                              hipStream_t stream) {
  Par p;
  p.input = (const float*)d_in[0];
  p.mask = (const float*)d_in[1];
  p.Wi = (const float*)d_in[2];
  p.bi = (const float*)d_in[3];
  p.gi = (const float*)d_in[4];
  p.bti = (const float*)d_in[5];
  p.Wd1 = (const float*)d_in[6];
  p.bd1 = (const float*)d_in[7];
  p.Wd2 = (const float*)d_in[8];
  p.bd2 = (const float*)d_in[9];
  p.Wc1 = (const float*)d_in[10];
  p.bc1 = (const float*)d_in[11];
  p.Wc2 = (const float*)d_in[12];
  p.bc2 = (const float*)d_in[13];
  p.gc = (const float*)d_in[14];
  p.btc = (const float*)d_in[15];
  p.out = (float*)d_out;

  float* ws = (float*)d_ws;
  size_t off = 0;
  p.bar = (unsigned int*)(ws + off); off += 256;
  p.pos = (int*)(ws + off); off += 128 * 64;
  p.ksel = (int*)(ws + off); off += 128;
  off = (off + 127) & ~(size_t)127;
  p.logits = ws + off; off += 128 * 64;
  p.x = ws + off; off += (size_t)128 * 1024;
  p.h = ws + off; off += (size_t)128 * 2048;
  p.ct = ws + off; off += (size_t)128 * 2048;
  p.cs = ws + off; off += (size_t)128 * 64 * 512;
  // total ~19.4 MB of d_ws

  hipLaunchKernelGGL(egt_zero, dim3(1), dim3(256), 0, stream, p.bar);
  void* args[] = {&p};
  hipError_t err = hipLaunchCooperativeKernel(egt_main, dim3(256), dim3(256), args, 0, stream);
  if (err != hipSuccess) {
    (void)hipGetLastError();  // clear sticky error; fall back to regular launch
    hipLaunchKernelGGL(egt_main, dim3(256), dim3(256), 0, stream, p);
  }
}

// Round 3
// 14770.732 us; speedup vs baseline: 1.5353x; 1.5353x over previous
//
#include <hip/hip_runtime.h>

#define NBATCH 128
#define DMODEL 512
#define FDIM 64
#define KIN 1024
#define NOUT 2048

struct Par {
  const float *input, *mask, *Wi, *bi, *gi, *bti;
  const float *Wd1, *bd1, *Wd2, *bd2;
  const float *Wc1, *bc1, *Wc2, *bc2, *gc, *btc;
  float *out;
  float *cs, *x, *h, *ct, *logits;
  int *pos, *ksel;
  unsigned int *bar;
};

__device__ __forceinline__ float gelu_f(float v) {
  float u = 0.7978845608028654f * (v + 0.044715f * v * v * v);
  return 0.5f * v * (1.0f + tanhf(u));
}
__device__ __forceinline__ float sigm_f(float v) { return 1.0f / (1.0f + expf(-v)); }

__device__ __forceinline__ float wred_sum(float v) {
#pragma unroll
  for (int o = 32; o > 0; o >>= 1) v += __shfl_xor(v, o, 64);
  return v;
}

// monotonic-counter grid barrier (256 co-resident blocks; agent scope = device)
__device__ __forceinline__ void gsync(unsigned int* bar, unsigned int* tgt) {
  __syncthreads();
  if (threadIdx.x == 0) {
    *tgt += gridDim.x;
    __hip_atomic_fetch_add(bar, 1u, __ATOMIC_ACQ_REL, __HIP_MEMORY_SCOPE_AGENT);
    while (__hip_atomic_load(bar, __ATOMIC_ACQUIRE, __HIP_MEMORY_SCOPE_AGENT) < *tgt)
      __builtin_amdgcn_s_sleep(1);
  }
  __syncthreads();
}

// ---- SEL: argmax + pos/logit shift + build x = [l_sel, r_sel] (block = row n)
__device__ void sel_phase(const Par& p, int i, int* sI) {
  int n = blockIdx.x;
  int t = threadIdx.x, wave = t >> 6, lane = t & 63;
  int P = 63 - i;
  if (wave == 0) {
    float v = -3.0e38f;
    int idx = 1 << 20;
    if (lane < P) {
      v = p.logits[n * 64 + lane];
      float mk = p.mask[n * 64 + i + 1 + lane];
      if (!(mk > 0.0f)) v = -1.0e9f;
      idx = lane;
    }
#pragma unroll
    for (int o = 32; o > 0; o >>= 1) {
      float v2 = __shfl_xor(v, o, 64);
      int i2 = __shfl_xor(idx, o, 64);
      if (v2 > v || (v2 == v && i2 < idx)) { v = v2; idx = i2; }
    }
    if (lane == 0) {
      p.ksel[n] = idx;
      sI[0] = idx;
      sI[1] = p.pos[n * 64 + idx];
      sI[2] = p.pos[n * 64 + idx + 1];
    }
  }
  __syncthreads();
  int k = sI[0], slot_l = sI[1], slot_r = sI[2];
  if (wave == 1) {  // shift pos (wave-lockstep load-before-store)
    int j = lane;
    if (j >= k + 1 && j <= 62 - i) {
      int tmp = p.pos[n * 64 + j + 1];
      p.pos[n * 64 + j] = tmp;
    }
  } else if (wave == 2) {  // shift logits
    int j = lane;
    if (j >= k && j <= 61 - i) {
      float tmp = p.logits[n * 64 + j + 1];
      p.logits[n * 64 + j] = tmp;
    }
  }
  const float4* csl = (const float4*)&p.cs[(size_t)(n * 64 + slot_l) * DMODEL];
  const float4* csr = (const float4*)&p.cs[(size_t)(n * 64 + slot_r) * DMODEL];
  float4* xd = (float4*)&p.x[(size_t)n * KIN];
  if (t < 128) xd[t] = csl[t];
  else if (t < 256) xd[t] = csr[t - 128];
}

// ---- GEMM1: h = gelu(x @ Wc1 + bc1); 8 Mtiles(16 rows) x 32 col-chunks(64)
//      512 threads: thread = (row = t>>5, colpair = (t&31)*2); K in 2 halves
__device__ void g1_phase(const Par& p, float* smem) {
  int b = blockIdx.x, t = threadIdx.x;
  int mt = b >> 5, nc = b & 31;  // nc%8 == b%8 -> XCD-local weight columns
  int rbase = mt * 16, cbase = nc * 64;
  float* xs = smem;  // [16][512]
  int row = t >> 5;
  int cg = cbase + (t & 31) * 2;
  int wcol = cg >> 1;
  const float2* W2 = (const float2*)p.Wc1;
  const int S = NOUT / 2;
  float a0 = 0.f, a1 = 0.f;
  for (int half = 0; half < 2; ++half) {
    __syncthreads();
#pragma unroll
    for (int q = 0; q < 4; ++q) {
      int flat = (q * 512 + t) * 4;
      int r = flat >> 9, c = flat & 511;
      *(float4*)&xs[flat] =
          *(const float4*)&p.x[(size_t)(rbase + r) * KIN + half * 512 + c];
    }
    __syncthreads();
    const float* x0 = xs + row * 512;
    const float2* Wp = W2 + (size_t)(half * 512) * S + wcol;
    float2 w0 = Wp[0], w1 = Wp[S], w2 = Wp[2 * S], w3 = Wp[3 * S];
    for (int k = 0; k < 512; k += 4) {
      int kn = (k + 4 < 512) ? (k + 4) : k;
      const float2* Wn = W2 + (size_t)(half * 512 + kn) * S + wcol;
      float2 n0 = Wn[0], n1 = Wn[S], n2 = Wn[2 * S], n3 = Wn[3 * S];
      float4 xa = *(const float4*)&x0[k];
      a0 += xa.x * w0.x; a1 += xa.x * w0.y;
      a0 += xa.y * w1.x; a1 += xa.y * w1.y;
      a0 += xa.z * w2.x; a1 += xa.z * w2.y;
      a0 += xa.w * w3.x; a1 += xa.w * w3.y;
      w0 = n0; w1 = n1; w2 = n2; w3 = n3;
    }
  }
  float2 bc = *(const float2*)&p.bc1[cg];
  *(float2*)&p.h[(size_t)(rbase + row) * NOUT + cg] =
      make_float2(gelu_f(a0 + bc.x), gelu_f(a1 + bc.y));
}

// ---- GEMM2: ct = h @ Wc2 + bc2; same tiling, K=2048 in 4 chunks
__device__ void g2_phase(const Par& p, float* smem) {
  int b = blockIdx.x, t = threadIdx.x;
  int mt = b >> 5, nc = b & 31;
  int rbase = mt * 16, cbase = nc * 64;
  float* hs = smem;  // [16][512]
  int row = t >> 5;
  int cg = cbase + (t & 31) * 2;
  int wcol = cg >> 1;
  const float2* W2 = (const float2*)p.Wc2;
  const int S = NOUT / 2;
  float a0 = 0.f, a1 = 0.f;
  for (int qtr = 0; qtr < 4; ++qtr) {
    __syncthreads();
#pragma unroll
    for (int q = 0; q < 4; ++q) {
      int flat = (q * 512 + t) * 4;
      int r = flat >> 9, c = flat & 511;
      *(float4*)&hs[flat] =
          *(const float4*)&p.h[(size_t)(rbase + r) * NOUT + qtr * 512 + c];
    }
    __syncthreads();
    const float* x0 = hs + row * 512;
    const float2* Wp = W2 + (size_t)(qtr * 512) * S + wcol;
    float2 w0 = Wp[0], w1 = Wp[S], w2 = Wp[2 * S], w3 = Wp[3 * S];
    for (int k = 0; k < 512; k += 4) {
      int kn = (k + 4 < 512) ? (k + 4) : k;
      const float2* Wn = W2 + (size_t)(qtr * 512 + kn) * S + wcol;
      float2 n0 = Wn[0], n1 = Wn[S], n2 = Wn[2 * S], n3 = Wn[3 * S];
      float4 xa = *(const float4*)&x0[k];
      a0 += xa.x * w0.x; a1 += xa.x * w0.y;
      a0 += xa.y * w1.x; a1 += xa.y * w1.y;
      a0 += xa.z * w2.x; a1 += xa.z * w2.y;
      a0 += xa.w * w3.x; a1 += xa.w * w3.y;
      w0 = n0; w1 = n1; w2 = n2; w3 = n3;
    }
  }
  float2 bc = *(const float2*)&p.bc2[cg];
  *(float2*)&p.ct[(size_t)(rbase + row) * NOUT + cg] =
      make_float2(a0 + bc.x, a1 + bc.y);
}

// ---- EPI: gates/blend/LN -> cs[slot_new]; recompute logits for pairs k-1, k
__device__ void epi_phase(const Par& p, int i, float* smem, float* sred) {
  int n = blockIdx.x;
  int t = threadIdx.x, wave = t >> 6, lane = t & 63;
  int Pn = 62 - i;
  int k = p.ksel[n];
  int slot_new = p.pos[n * 64 + k];
  float* s_wd1 = smem;          // 8192 floats
  float* s_wd2 = smem + 8192;   // 64
  float* s_bd1 = smem + 8256;   // 64
  float* s_fnew = smem + 8320;  // 64
  if (i < 62) {
#pragma unroll
    for (int q = 0; q < 4; ++q)
      ((float4*)s_wd1)[q * 512 + t] = ((const float4*)p.Wd1)[q * 512 + t];
    if (t < 64) { s_wd2[t] = p.Wd2[t]; s_bd1[t] = p.bd1[t]; }
  }
  const float* ct = p.ct + (size_t)n * NOUT;
  int d = t;  // 512 threads = 512 dims
  float lv = p.x[(size_t)n * KIN + d];
  float rv = p.x[(size_t)n * KIN + DMODEL + d];
  float c0 = ct[d], c1 = ct[DMODEL + d], c2 = ct[2 * DMODEL + d], c3 = ct[3 * DMODEL + d];
  float s = sigm_f(c0) * lv + sigm_f(c1) * rv + sigm_f(c2) * c3;
  float part = wred_sum(s);
  if (lane == 0) sred[wave] = part;
  __syncthreads();
  float m = 0.f;
#pragma unroll
  for (int w = 0; w < 8; ++w) m += sred[w];
  m *= (1.0f / 512.0f);
  float e = s - m;
  float pq = wred_sum(e * e);
  if (lane == 0) sred[8 + wave] = pq;
  __syncthreads();
  float var = 0.f;
#pragma unroll
  for (int w = 0; w < 8; ++w) var += sred[8 + w];
  var *= (1.0f / 512.0f);
  float inv = 1.0f / sqrtf(var + 1e-5f);
  float nv = e * inv * p.gc[d] + p.btc[d];
  p.cs[(size_t)(n * 64 + slot_new) * DMODEL + d] = nv;
  if (i == 62) p.out[(size_t)n * DMODEL + d] = nv;
  if (d < FDIM) s_fnew[d] = nv;
  __syncthreads();
  if (i < 62) {
    if (wave == 0 && k >= 1) {
      const float* A = &p.cs[(size_t)(n * 64 + p.pos[n * 64 + (k - 1)]) * DMODEL];
      float hs = s_bd1[lane];
#pragma unroll 8
      for (int kk = 0; kk < 64; ++kk) hs += A[kk] * s_wd1[kk * 64 + lane];
#pragma unroll 8
      for (int kk = 0; kk < 64; ++kk) hs += s_fnew[kk] * s_wd1[(64 + kk) * 64 + lane];
      float g = wred_sum(gelu_f(hs) * s_wd2[lane]);
      if (lane == 0) p.logits[n * 64 + (k - 1)] = g + p.bd2[0];
    } else if (wave == 1 && k < Pn) {
      const float* Bv = &p.cs[(size_t)(n * 64 + p.pos[n * 64 + (k + 1)]) * DMODEL];
      float hs = s_bd1[lane];
#pragma unroll 8
      for (int kk = 0; kk < 64; ++kk) hs += s_fnew[kk] * s_wd1[kk * 64 + lane];
#pragma unroll 8
      for (int kk = 0; kk < 64; ++kk) hs += Bv[kk] * s_wd1[(64 + kk) * 64 + lane];
      float g = wred_sum(gelu_f(hs) * s_wd2[lane]);
      if (lane == 0) p.logits[n * 64 + k] = g + p.bd2[0];
    }
  }
}

__global__ void egt_zero(unsigned int* bar) { bar[threadIdx.x] = 0u; }

__global__ void __launch_bounds__(512, 2) egt_main(Par p) {
  __shared__ __align__(16) float smem[12480];  // 49.9 KB
  __shared__ float sred[16];
  __shared__ int sI[8];
  unsigned int nsync = 0;
  int b = blockIdx.x, t = threadIdx.x;
  int wave = t >> 6, lane = t & 63;

  // ---------- INIT-PROJ: cs0 = LN(input @ Wi + bi); 32 (n,s)-rows per block
  {
    int rbase = b * 32;
    int n_ = b >> 1;
    float acc[32];
#pragma unroll
    for (int r = 0; r < 32; ++r) acc[r] = 0.f;
    float* xs = smem;  // [32][64]
    const float* Wi = p.Wi;
    for (int kc = 0; kc < 512; kc += 64) {
      __syncthreads();
      {
        int flat = t * 4;  // 512 threads x float4 = 2048 floats
        int r = flat >> 6, c = flat & 63;
        *(float4*)&xs[flat] =
            *(const float4*)&p.input[(size_t)(rbase + r) * 512 + kc + c];
      }
      __syncthreads();
      for (int k = 0; k < 64; k += 4) {
        float w0 = Wi[(size_t)(kc + k + 0) * 512 + t];
        float w1 = Wi[(size_t)(kc + k + 1) * 512 + t];
        float w2 = Wi[(size_t)(kc + k + 2) * 512 + t];
        float w3 = Wi[(size_t)(kc + k + 3) * 512 + t];
#pragma unroll
        for (int r = 0; r < 32; ++r) {
          float4 xv = *(const float4*)&xs[r * 64 + k];
          acc[r] += xv.x * w0 + xv.y * w1 + xv.z * w2 + xv.w * w3;
        }
      }
    }
    float* row8 = smem;  // [8][512]
#pragma unroll
    for (int chunk = 0; chunk < 4; ++chunk) {
      __syncthreads();
#pragma unroll
      for (int rr = 0; rr < 8; ++rr)
        row8[rr * 512 + t] = acc[chunk * 8 + rr] + p.bi[t];
      __syncthreads();
      int rr = wave;  // 8 waves -> 8 rows
      float vals[8];
      float sum = 0.f;
#pragma unroll
      for (int jj = 0; jj < 8; ++jj) {
        float v = row8[rr * 512 + jj * 64 + lane];
        vals[jj] = v;
        sum += v;
      }
      sum = wred_sum(sum);
      float mm = sum * (1.0f / 512.0f);
      float sq = 0.f;
#pragma unroll
      for (int jj = 0; jj < 8; ++jj) { float dd = vals[jj] - mm; sq += dd * dd; }
      sq = wred_sum(sq);
      float inv = 1.0f / sqrtf(sq * (1.0f / 512.0f) + 1e-5f);
      int r = chunk * 8 + rr;
      int ss = (b & 1) * 32 + r;
      float* dst = &p.cs[(size_t)(n_ * 64 + ss) * DMODEL];
#pragma unroll
      for (int jj = 0; jj < 8; ++jj) {
        int c = jj * 64 + lane;
        dst[c] = (vals[jj] - mm) * inv * p.gi[c] + p.bti[c];
      }
    }
  }
  gsync(p.bar, &nsync);

  // ---------- INIT-SCORE: 63 pair logits per row; init pos; SEL(0)
  if (b < NBATCH) {
    int n = b;
    float* s_wd1 = smem;          // 8192 floats
    float* s_f = smem + 8192;     // 4096 floats: 64 slots x first-64 dims
    float* s_wd2 = smem + 12288;  // 64
    float* s_bd1 = smem + 12352;  // 64
#pragma unroll
    for (int q = 0; q < 4; ++q)
      ((float4*)s_wd1)[q * 512 + t] = ((const float4*)p.Wd1)[q * 512 + t];
#pragma unroll
    for (int q = 0; q < 2; ++q) {
      int i4 = q * 512 + t;
      int s = i4 >> 4, c = (i4 & 15) * 4;
      *(float4*)&s_f[s * 64 + c] =
          *(const float4*)&p.cs[(size_t)(n * 64 + s) * DMODEL + c];
    }
    if (t < 64) {
      s_wd2[t] = p.Wd2[t];
      s_bd1[t] = p.bd1[t];
      p.pos[n * 64 + t] = t;
    }
    __syncthreads();
    for (int pr = wave; pr < 63; pr += 8) {
      float hs = s_bd1[lane];
#pragma unroll 8
      for (int kk = 0; kk < 64; ++kk) hs += s_f[pr * 64 + kk] * s_wd1[kk * 64 + lane];
#pragma unroll 8
      for (int kk = 0; kk < 64; ++kk) hs += s_f[(pr + 1) * 64 + kk] * s_wd1[(64 + kk) * 64 + lane];
      float g = wred_sum(gelu_f(hs) * s_wd2[lane]);
      if (lane == 0) p.logits[n * 64 + pr] = g + p.bd2[0];
    }
    __syncthreads();
    sel_phase(p, 0, sI);
  }
  gsync(p.bar, &nsync);

  // ---------- main serial loop
  for (int i = 0; i < 63; ++i) {
    g1_phase(p, smem);
    gsync(p.bar, &nsync);
    g2_phase(p, smem);
    gsync(p.bar, &nsync);
    if (b < NBATCH) {
      epi_phase(p, i, smem, sred);
      if (i < 62) {
        __syncthreads();
        sel_phase(p, i + 1, sI);
      }
    }
    gsync(p.bar, &nsync);
  }
}

extern "C" void kernel_launch(void* const* d_in, const int* in_sizes, int n_in,
                              void* d_out, int out_size, void* d_ws, size_t ws_size,
                              hipStream_t stream) {
  Par p;
  p.input = (const float*)d_in[0];
  p.mask = (const float*)d_in[1];
  p.Wi = (const float*)d_in[2];
  p.bi = (const float*)d_in[3];
  p.gi = (const float*)d_in[4];
  p.bti = (const float*)d_in[5];
  p.Wd1 = (const float*)d_in[6];
  p.bd1 = (const float*)d_in[7];
  p.Wd2 = (const float*)d_in[8];
  p.bd2 = (const float*)d_in[9];
  p.Wc1 = (const float*)d_in[10];
  p.bc1 = (const float*)d_in[11];
  p.Wc2 = (const float*)d_in[12];
  p.bc2 = (const float*)d_in[13];
  p.gc = (const float*)d_in[14];
  p.btc = (const float*)d_in[15];
  p.out = (float*)d_out;

  float* ws = (float*)d_ws;
  size_t off = 0;
  p.bar = (unsigned int*)(ws + off); off += 256;
  p.pos = (int*)(ws + off); off += 128 * 64;
  p.ksel = (int*)(ws + off); off += 128;
  off = (off + 127) & ~(size_t)127;
  p.logits = ws + off; off += 128 * 64;
  p.x = ws + off; off += (size_t)128 * 1024;
  p.h = ws + off; off += (size_t)128 * 2048;
  p.ct = ws + off; off += (size_t)128 * 2048;
  p.cs = ws + off; off += (size_t)128 * 64 * 512;

  hipLaunchKernelGGL(egt_zero, dim3(1), dim3(256), 0, stream, p.bar);
  void* args[] = {&p};
  hipError_t err = hipLaunchCooperativeKernel(egt_main, dim3(256), dim3(512), args, 0, stream);
  if (err != hipSuccess) {
    (void)hipGetLastError();  // clear sticky error; manual barrier works either way
    hipLaunchKernelGGL(egt_main, dim3(256), dim3(512), 0, stream, p);
  }
}